// Round 8
// baseline (133.519 us; speedup 1.0000x reference)
//
#include <hip/hip_runtime.h>

// Problem constants
#define NB 32768
#define NT 16
#define NV 32001   // V+1
#define NE 32
#define NTAGS 64

typedef __attribute__((ext_vector_type(8))) short short8;   // 8 bf16 (4 VGPR)
typedef __attribute__((ext_vector_type(4))) float f4;       // MFMA acc

#define MFMA16(a, b, c) __builtin_amdgcn_mfma_f32_16x16x32_bf16(a, b, c, 0, 0, 0)
// DS ops are in-order within a wave -> compiler-only fence suffices for same-wave LDS RAW
#define CFENCE() asm volatile("" ::: "memory")
#define LDSSYNC() asm volatile("s_waitcnt lgkmcnt(0)" ::: "memory")

#define NL2E  (-1.44269504f)   // -log2(e)
#define NL2E2 (-2.88539008f)   // -2*log2(e)

__device__ __forceinline__ float exp2_(float x) {  // raw v_exp_f32 (D = 2^S0)
    float r;
    asm("v_exp_f32 %0, %1" : "=v"(r) : "v"(x));
    return r;
}
__device__ __forceinline__ float sigm_(float x) {
    return __builtin_amdgcn_rcpf(1.0f + __expf(-x));
}
__device__ __forceinline__ float tanh2_(float x) {  // 2*sigm(2x)-1
    float e = __expf(-2.0f * x);
    return fmaf(2.0f, __builtin_amdgcn_rcpf(1.0f + e), -1.0f);
}
__device__ __forceinline__ float tanh2e_(float x) {  // tanh via exp2: one mul on the chain
    return fmaf(2.0f, __builtin_amdgcn_rcpf(1.0f + exp2_(x * NL2E2)), -1.0f);
}
__device__ __forceinline__ short f2bf(float x) {  // RNE float->bf16 bits
    union { float f; unsigned u; } v; v.f = x;
    unsigned r = v.u + 0x7fffu + ((v.u >> 16) & 1u);
    return (short)(r >> 16);
}
// packed RNE float2->bf16x2 (gfx950 v_cvt_pk_bf16_f32; bit-identical to f2bf for normals)
__device__ __forceinline__ void pk2bf(float a, float b, short& lo, short& hi) {
    unsigned r;
    asm("v_cvt_pk_bf16_f32 %0, %1, %2" : "=v"(r) : "v"(a), "v"(b));
    lo = (short)r;
    hi = (short)(r >> 16);
}

// ---------------- K1: classify (32 slabs, no atomics) + emb->bf16 + weight pack ----------------
__global__ __launch_bounds__(1024) void classify_prep(
    const int* __restrict__ s, const float* __restrict__ emb,
    const float* __restrict__ Wih, const float* __restrict__ Whh,
    const float* __restrict__ bih, const float* __restrict__ bhh,
    const float* __restrict__ Wc, const float* __restrict__ Wt,
    short* __restrict__ embH, short* __restrict__ wpack, short* __restrict__ wc1,
    short* __restrict__ wc2, short* __restrict__ wth, float* __restrict__ bsum,
    int* __restrict__ cH, int* __restrict__ listH, int* __restrict__ listL) {
    __shared__ int wbH[16], wbL[16];
    const int tid = threadIdx.x, b = blockIdx.x;
    if (b < 32) {
        const int row = b * 1024 + tid;
        const bool heavy = s[row] >= 4;
        unsigned long long mk = __ballot(heavy);
        const int wv = tid >> 6, ln = tid & 63;
        if (ln == 0) wbH[wv] = __popcll(mk);
        __syncthreads();
        if (tid == 0) {
            int tH = 0, tL = 0;
#pragma unroll
            for (int i = 0; i < 16; ++i) {
                int ch = wbH[i];
                wbH[i] = tH; wbL[i] = tL;
                tH += ch; tL += 64 - ch;
            }
            cH[b] = tH;
        }
        __syncthreads();
        unsigned long long ltm = (1ull << ln) - 1ull;
        if (heavy) listH[b * 1024 + wbH[wv] + __popcll(mk & ltm)] = row;
        else       listL[b * 1024 + wbL[wv] + __popcll((~mk) & ltm)] = row;
    }
    // emb -> bf16: one float4 -> short4 per thread (256008 float4s <= 262144 threads)
    {
        const int i4 = b * 1024 + tid;
        if (i4 < (NV * NE) / 4) {
            const float4 vs = ((const float4*)emb)[i4];
            short p0, p1, p2, p3;
            pk2bf(vs.x, vs.y, p0, p1);
            pk2bf(vs.z, vs.w, p2, p3);
            short4 o; o.x = p0; o.y = p1; o.z = p2; o.w = p3;
            ((short4*)embH)[i4] = o;
        }
    }
    if (b == 32) {        // Whh -> wpack[256][72] (zero-padded)
        for (int t = tid; t < 18432; t += 1024) {
            int r = t / 72, c = t % 72;
            wpack[t] = f2bf(c < 64 ? Whh[r * 64 + c] : 0.f);
        }
    } else if (b == 33) { // Wih -> wpack+18432 [256][40] (zero-padded)
        for (int t = tid; t < 10240; t += 1024) {
            int r = t / 40, c = t % 40;
            wpack[18432 + t] = f2bf(c < 32 ? Wih[r * 32 + c] : 0.f);
        }
    } else if (b == 34) { // Wc split
        if (tid < 1024) { int r = tid >> 5, c = tid & 31; wc1[tid] = f2bf(Wc[r * 96 + c]); }
        for (int t = tid; t < 2048; t += 1024) {
            int r = t >> 6, c = t & 63;
            wc2[t] = f2bf(Wc[r * 96 + 32 + c]);
        }
    } else if (b == 35) { // Wt + bias sum
        for (int t = tid; t < 2048; t += 1024) {
            int r = t >> 5, c = t & 31;
            wth[t] = f2bf(Wt[r * 32 + c]);
        }
        if (tid < 256) bsum[tid] = bih[tid] + bhh[tid];
    }
}

// ---------------- K2: fused main — heavy (block-cooperative, 16 rows/block) + light (MFMA) -----
// __launch_bounds__(256, 2). R8: (a) wihP[16] Wih fragments hoisted above the whole heavy section
// (loop-invariant; 64 VGPR; peak co-residency ~210 < 256 -> same 2 waves/SIMD band, no spill);
// phase-2 reuses wihP[j*4+wave]. (b) post-c4 barrier removed: all waves compute identical c4
// (inputs barrier-synced), so each wave writes its own full 16-row copy and reads it back with
// only an in-wave fence. (c) tanh on the c-chain via exp2 (one mul shorter dependent chain).
__global__ __launch_bounds__(256, 2) void main_fused(
    const int* __restrict__ x, const float* __restrict__ emb,
    const float* __restrict__ h0, const float* __restrict__ c0,
    const float* __restrict__ Wc, const float* __restrict__ bc,
    const float* __restrict__ Wt, const float* __restrict__ bt,
    const float* __restrict__ bsum,
    const short* __restrict__ wpack, const short* __restrict__ wc1,
    const short* __restrict__ wc2, const short* __restrict__ wth,
    const short* __restrict__ embH, const int* __restrict__ cH,
    const int* __restrict__ listH, const int* __restrict__ listL,
    float* __restrict__ out) {
    __shared__ __align__(16) short sWhh[18432];      // 36 KB [256][72] bf16
    __shared__ __align__(16) short sHA[4][16 * 72];  // phase1: per-wave h; phase2: sHA[0]/sHA[1] dbuf
    __shared__ __align__(16) short sCmb[4][16 * 40]; // heavy: block cmbB[node*16+row][40]; light: per-wave
    __shared__ __align__(16) short sC4[4][4 * 40];   // heavy: block c4[16 rows][40]
    __shared__ int sRow[16];                         // heavy: global row ids of the block's 16 rows

    const int tid = threadIdx.x, wave = tid >> 6, lane = tid & 63;
    const int q = lane >> 4, n = lane & 15;
    const int NW = gridDim.x * 4;  // 2048
    const int gw = blockIdx.x * 4 + wave;

    // 32-slab prefix scan (per wave, shfl)
    int cs = (lane < 32) ? cH[lane] : 0;
    int v = cs;
#pragma unroll
    for (int o = 1; o < 32; o <<= 1) { int t2 = __shfl_up(v, o); if (lane >= o) v += t2; }
    const int vIncl = v, vExcl = v - cs;
    const int nH = __shfl(vIncl, 31);
    const int nL = NB - nH;
    const int liIncl = (lane + 1) * 1024 - vIncl;  // light prefixes (lane<32)
    const int liExcl = lane * 1024 - vExcl;
    const int nHB = (nH + 15) >> 4;                // heavy BLOCK count (16 rows/block)
    const bool heavyBlk = (int)blockIdx.x < nHB;
    const short* wihG = wpack + 18432;             // Wih [256][40] bf16 — global (L2-resident)

    // ---- prologue hoist: first heavy iteration's gathers issued BEFORE staging ----
    int row0 = 0, tokAll0 = 0;
    short8 aNext0;
    const int liBase = (n & 3) * 16 + (n >> 2) * 4;  // unit n: row n&3, node n>>2
    if (heavyBlk) {
        int idxq = min((int)blockIdx.x * 16 + wave * 4 + q, nH - 1);
        int sl = 0;
#pragma unroll
        for (int b2 = 0; b2 < 32; ++b2) sl += (__shfl(vIncl, b2) <= idxq) ? 1 : 0;
        row0 = listH[sl * 1024 + idxq - __shfl(vExcl, sl)];
        tokAll0 = x[row0 * 16 + n];
        aNext0 = *(const short8*)&embH[__shfl(tokAll0, liBase) * 32 + q * 8];
    }

    if (heavyBlk) {  // block-uniform: only heavy blocks stage Whh
        for (int i = tid; i < 2304; i += 256)
            ((uint4*)sWhh)[i] = ((const uint4*)wpack)[i];
        __syncthreads();
    }

    if (heavyBlk) {
        short* hA = sHA[wave];        // phase1 private slice
        short* cmbB = sCmb[0];        // [64][40] block-level: node*16 + blockrow
        short* c4 = sC4[0];           // [16][40] block-level

        // scaled gate biases: tiles 0-7 (i,f) and 12-15 (o): -log2e*b; tiles 8-11 (g): -2log2e*b
        float sb16[16];
#pragma unroll
        for (int tl = 0; tl < 16; ++tl)
            sb16[tl] = (((tl >> 2) == 2) ? NL2E2 : NL2E) * bsum[tl * 16 + n];
        float bc2[2] = {bc[n], bc[16 + n]};
        float bt4[4] = {bt[n], bt[16 + n], bt[32 + n], bt[48 + n]};
        float c0v[4];
#pragma unroll
        for (int u = 0; u < 4; ++u) c0v[u] = c0[u * 16 + n];
        // h0 A-fragments (step-0 Whh operand is h0 for every row)
        short8 h0f0, h0f1;
#pragma unroll
        for (int j = 0; j < 8; ++j) {
            h0f0[j] = f2bf(h0[q * 8 + j]);
            h0f1[j] = f2bf(h0[32 + q * 8 + j]);
        }
        const float c0w = c0[wave * 16 + n];  // phase2: this wave's unit block

        // Wih fragments: loop/step-invariant -> load ONCE for the whole heavy section (64 VGPR).
        short8 wihP[16];
#pragma unroll
        for (int tl = 0; tl < 16; ++tl)
            wihP[tl] = *(const short8*)&wihG[(tl * 16 + n) * 40 + q * 8];

        const f4 zero4 = {0.f, 0.f, 0.f, 0.f};
        float cst[4][4];

        // one half-step: 8 tiles {g*4+u0, g*4+u0+1 : g in 0..3}, gate updates for u0,u0+1.
        auto halfStep = [&](int u0, short8 aP, short8 ah0, short8 ah1, bool doRelu) {
            f4 acc8[8];
#pragma unroll
            for (int g = 0; g < 4; ++g)
#pragma unroll
                for (int k = 0; k < 2; ++k)
                    acc8[g * 2 + k] = MFMA16(aP, wihP[g * 4 + u0 + k], zero4);
#pragma unroll
            for (int g = 0; g < 4; ++g)
#pragma unroll
                for (int k = 0; k < 2; ++k) {
                    const short* rbp = &sWhh[((g * 4 + u0 + k) * 16 + n) * 72 + q * 8];
                    f4 t0 = acc8[g * 2 + k];
                    t0 = MFMA16(ah0, *(const short8*)rbp, t0);
                    t0 = MFMA16(ah1, *(const short8*)(rbp + 32), t0);
                    acc8[g * 2 + k] = t0;
                }
#pragma unroll
            for (int k = 0; k < 2; ++k) {
                const int u = u0 + k;
                float hv[4];
#pragma unroll
                for (int r = 0; r < 4; ++r) {
                    float si = __builtin_amdgcn_rcpf(
                        1.0f + exp2_(fmaf(acc8[0 + k][r], NL2E, sb16[u])));
                    float sf = __builtin_amdgcn_rcpf(
                        1.0f + exp2_(fmaf(acc8[2 + k][r], NL2E, sb16[4 + u])));
                    float tg = fmaf(2.0f, __builtin_amdgcn_rcpf(
                        1.0f + exp2_(fmaf(acc8[4 + k][r], NL2E2, sb16[8 + u]))), -1.0f);
                    float so = __builtin_amdgcn_rcpf(
                        1.0f + exp2_(fmaf(acc8[6 + k][r], NL2E, sb16[12 + u])));
                    float cc = fmaf(sf, cst[r][u], si * tg);
                    cst[r][u] = cc;
                    float hh = so * tanh2e_(cc);
                    if (doRelu) hh = fmaxf(hh, 0.f);
                    hv[r] = hh;
                }
                short p0, p1, p2, p3;
                pk2bf(hv[0], hv[1], p0, p1);
                pk2bf(hv[2], hv[3], p2, p3);
                hA[(q * 4 + 0) * 72 + u * 16 + n] = p0;
                hA[(q * 4 + 1) * 72 + u * 16 + n] = p1;
                hA[(q * 4 + 2) * 72 + u * 16 + n] = p2;
                hA[(q * 4 + 3) * 72 + u * 16 + n] = p3;
            }
        };

#pragma unroll 1
        for (int itb = blockIdx.x; itb * 16 < nH; itb += (int)gridDim.x) {
            const int base = itb * 16;
            int row, tokAll;
            short8 aNext;
            if (itb == (int)blockIdx.x) {  // wave-uniform branch: use hoisted prologue
                row = row0; tokAll = tokAll0; aNext = aNext0;
            } else {
                int idxq = min(base + wave * 4 + q, nH - 1);
                int sl = 0;
#pragma unroll
                for (int b2 = 0; b2 < 32; ++b2) sl += (__shfl(vIncl, b2) <= idxq) ? 1 : 0;
                row = listH[sl * 1024 + idxq - __shfl(vExcl, sl)];
                tokAll = x[row * 16 + n];
                aNext = *(const short8*)&embH[__shfl(tokAll, liBase) * 32 + q * 8];
            }
            if (n == 0) sRow[wave * 4 + q] = row;       // own slots only (no cross-wave race)
            const int tokR0 = __shfl(tokAll, liBase);   // root token (frag reloaded at comb)

            // ---- phase 1: this wave's 4 rows x 4 nodes in the 16 units, 4 steps ----
#pragma unroll
            for (int u = 0; u < 4; ++u)
#pragma unroll
                for (int r = 0; r < 4; ++r) cst[r][u] = c0v[u];
            short8 a0 = h0f0, a1 = h0f1;
#pragma unroll 1
            for (int t = 0; t < 4; ++t) {
                short8 aP = aNext;
                if (t < 3) {
                    int tk2 = __shfl(tokAll, liBase + t + 1);
                    aNext = *(const short8*)&embH[tk2 * 32 + q * 8];
                }
                halfStep(0, aP, a0, a1, t == 3);
                halfStep(2, aP, a0, a1, t == 3);  // step 3 writes relu(h) = "last"
                CFENCE();                          // order h ds_writes before the re-read below
                if (t < 3) {
                    a0 = *(const short8*)&hA[n * 72 + q * 8];
                    a1 = *(const short8*)&hA[n * 72 + 32 + q * 8];
                }
            }
            // comb for 16 (node,row) pairs -> block cmbB[node*16 + blockrow][40]
            {
                short8 aRoot = *(const short8*)&embH[tokR0 * 32 + q * 8];  // L2-resident reload
                short8 lh0 = *(const short8*)&hA[n * 72 + q * 8];
                short8 lh1 = *(const short8*)&hA[n * 72 + 32 + q * 8];
#pragma unroll
                for (int tl2 = 0; tl2 < 2; ++tl2) {
                    float bv = bc2[tl2];
                    f4 t0 = {bv, bv, bv, bv};
                    short8 b1 = *(const short8*)&wc1[(tl2 * 16 + n) * 32 + q * 8];
                    t0 = MFMA16(aRoot, b1, t0);
                    const short* rbp = &wc2[(tl2 * 16 + n) * 64 + q * 8];
                    t0 = MFMA16(lh0, *(const short8*)rbp, t0);
                    t0 = MFMA16(lh1, *(const short8*)(rbp + 32), t0);
                    // node = q, local rows r consecutive -> pack converts
                    short p0, p1, p2, p3;
                    pk2bf(fmaxf(t0[0], 0.f), fmaxf(t0[1], 0.f), p0, p1);
                    pk2bf(fmaxf(t0[2], 0.f), fmaxf(t0[3], 0.f), p2, p3);
                    short* db = &cmbB[(q * 16 + wave * 4) * 40 + tl2 * 16 + n];
                    db[0 * 40] = p0; db[1 * 40] = p1; db[2 * 40] = p2; db[3 * 40] = p3;
                }
            }
            // phase2-invariant Whh B-frags + scaled bias: hoist BEFORE barrier
            float sb4[4];
            short8 whhA[4], whhB[4];
#pragma unroll
            for (int j = 0; j < 4; ++j) {
                sb4[j] = ((j == 2) ? NL2E2 : NL2E) * bsum[(j * 4 + wave) * 16 + n];
                const short* rbp = &sWhh[((j * 4 + wave) * 16 + n) * 72 + q * 8];
                whhA[j] = *(const short8*)rbp;
                whhB[j] = *(const short8*)(rbp + 32);
            }
            __syncthreads();  // cmbB + sRow complete; per-wave hA free after this point

            // ---- phase 2: node 4 for all 16 block rows, unit-block = wave; ROLLED loop,
            //      aC-MFMA pipelined one step ahead (Wih frags from wihP) ----
            {
                float cstw[4] = {c0w, c0w, c0w, c0w};
                short8 b0 = h0f0, b1 = h0f1;
                f4 acPre[4];
                {
                    short8 aC0 = *(const short8*)&cmbB[(0 * 16 + n) * 40 + q * 8];
#pragma unroll
                    for (int j = 0; j < 4; ++j) acPre[j] = MFMA16(aC0, wihP[j * 4 + wave], zero4);
                }
                short8 aCn = *(const short8*)&cmbB[(1 * 16 + n) * 40 + q * 8];
#pragma unroll 1
                for (int t = 0; t < 4; ++t) {
                    short* hbw = (t & 1) ? sHA[1] : sHA[0];  // ternary select (reg, no scratch)
                    f4 ac4[4];
#pragma unroll
                    for (int j = 0; j < 4; ++j) {
                        f4 t0 = MFMA16(b0, whhA[j], acPre[j]);
                        t0 = MFMA16(b1, whhB[j], t0);
                        ac4[j] = t0;
                    }
                    // prefetch next step's aC products (h-independent; t=3's is dead work)
#pragma unroll
                    for (int j = 0; j < 4; ++j) acPre[j] = MFMA16(aCn, wihP[j * 4 + wave], zero4);
                    aCn = *(const short8*)&cmbB[(((t + 2) & 3) * 16 + n) * 40 + q * 8];
                    float hv[4];
#pragma unroll
                    for (int r = 0; r < 4; ++r) {
                        float si = __builtin_amdgcn_rcpf(
                            1.0f + exp2_(fmaf(ac4[0][r], NL2E, sb4[0])));
                        float sf = __builtin_amdgcn_rcpf(
                            1.0f + exp2_(fmaf(ac4[1][r], NL2E, sb4[1])));
                        float tg = fmaf(2.0f, __builtin_amdgcn_rcpf(
                            1.0f + exp2_(fmaf(ac4[2][r], NL2E2, sb4[2]))), -1.0f);
                        float so = __builtin_amdgcn_rcpf(
                            1.0f + exp2_(fmaf(ac4[3][r], NL2E, sb4[3])));
                        float cc = fmaf(sf, cstw[r], si * tg);
                        cstw[r] = cc;
                        float hh = so * tanh2e_(cc);
                        if (t == 3) hh = fmaxf(hh, 0.f);
                        hv[r] = hh;
                    }
                    short p0, p1, p2, p3;
                    pk2bf(hv[0], hv[1], p0, p1);
                    pk2bf(hv[2], hv[3], p2, p3);
                    hbw[(q * 4 + 0) * 72 + wave * 16 + n] = p0;
                    hbw[(q * 4 + 1) * 72 + wave * 16 + n] = p1;
                    hbw[(q * 4 + 2) * 72 + wave * 16 + n] = p2;
                    hbw[(q * 4 + 3) * 72 + wave * 16 + n] = p3;
                    __syncthreads();  // all unit slices of this step visible (full fence)
                    b0 = *(const short8*)&hbw[n * 72 + q * 8];
                    b1 = *(const short8*)&hbw[n * 72 + 32 + q * 8];
                }
            }

            // ---- c4 = relu([root,last]@Wc^T+bc) for 16 rows. ALL inputs are identical across
            //      waves (barrier-synced), so every wave writes its own full copy (same bytes,
            //      benign) and reads it back with only an in-wave fence — NO barrier. ----
            {
                const short* hL = sHA[1];  // t=3 buffer
                int rv = sRow[n];
                int tokR = x[rv * 16];
                short8 aR = *(const short8*)&embH[tokR * 32 + q * 8];
                short8 lb0 = *(const short8*)&hL[n * 72 + q * 8];
                short8 lb1 = *(const short8*)&hL[n * 72 + 32 + q * 8];
#pragma unroll
                for (int tl2 = 0; tl2 < 2; ++tl2) {
                    float bv = bc2[tl2];
                    f4 t0 = {bv, bv, bv, bv};
                    short8 b1f = *(const short8*)&wc1[(tl2 * 16 + n) * 32 + q * 8];
                    t0 = MFMA16(aR, b1f, t0);
                    const short* rbp = &wc2[(tl2 * 16 + n) * 64 + q * 8];
                    t0 = MFMA16(lb0, *(const short8*)rbp, t0);
                    t0 = MFMA16(lb1, *(const short8*)(rbp + 32), t0);
                    short p0, p1, p2, p3;
                    pk2bf(fmaxf(t0[0], 0.f), fmaxf(t0[1], 0.f), p0, p1);
                    pk2bf(fmaxf(t0[2], 0.f), fmaxf(t0[3], 0.f), p2, p3);
                    short* db = &c4[(q * 4) * 40 + tl2 * 16 + n];  // quad q owns rows q*4+r
                    db[0 * 40] = p0; db[1 * 40] = p1; db[2 * 40] = p2; db[3 * 40] = p3;
                }
            }
            CFENCE();  // same-wave DS in-order: our own 16-row copy is readable

            // ---- phase 3: logits + log_softmax for 16 rows (dup compute, split writes) ----
            {
                short8 cA = *(const short8*)&c4[n * 40 + q * 8];
                f4 a3[4];
#pragma unroll
                for (int tl3 = 0; tl3 < 4; ++tl3) {
                    float bv = bt4[tl3];
                    f4 t0 = {bv, bv, bv, bv};
                    short8 bW = *(const short8*)&wth[(tl3 * 16 + n) * 32 + q * 8];
                    a3[tl3] = MFMA16(cA, bW, t0);
                }
#pragma unroll
                for (int r = 0; r < 4; ++r) {
                    float l0 = a3[0][r], l1 = a3[1][r], l2 = a3[2][r], l3 = a3[3][r];
                    float mx = fmaxf(fmaxf(l0, l1), fmaxf(l2, l3));
#pragma unroll
                    for (int o2 = 8; o2; o2 >>= 1) mx = fmaxf(mx, __shfl_xor(mx, o2));
                    float sm = __expf(l0 - mx) + __expf(l1 - mx) +
                               __expf(l2 - mx) + __expf(l3 - mx);
#pragma unroll
                    for (int o2 = 8; o2; o2 >>= 1) sm += __shfl_xor(sm, o2);
                    float lse = mx + __logf(sm);
                    if (q == wave && base + wave * 4 + r < nH) {
                        int ro = sRow[wave * 4 + r];
                        out[ro * 64 + n] = l0 - lse;
                        out[ro * 64 + 16 + n] = l1 - lse;
                        out[ro * 64 + 32 + n] = l2 - lse;
                        out[ro * 64 + 48 + n] = l3 - lse;
                    }
                }
            }
            // guard next iteration's shared writes vs this iteration's reads (multi-iter only;
            // with grid == nHB this is dead code)
            if ((itb + (int)gridDim.x) * 16 < nH) __syncthreads();
        }
    }

    // ---- light rows: 16 rows/iteration via MFMA, reverse-mapped over ALL waves so light
    //      overlaps the heavy tail (heavy waves pick up light as they finish) ----
    if (nL > 0) {
        const int lw = NW - 1 - gw;
        const int base0 = lw * 16;
        if (base0 < nL) {
            short* cmbL = sCmb[wave];  // safe: all waves of this block are past phase-2 reads
            f4 bcV[2], btV[4];
#pragma unroll
            for (int t = 0; t < 2; ++t) { float bv = bc[t * 16 + n]; bcV[t] = f4{bv, bv, bv, bv}; }
#pragma unroll
            for (int t = 0; t < 4; ++t) { float bv = bt[t * 16 + n]; btV[t] = f4{bv, bv, bv, bv}; }
#pragma unroll 1
            for (int base = base0; base < nL; base += NW * 16) {
                int idx = min(base + (lane & 15), nL - 1);  // 16 rows only (no 4x gather waste)
                int sl = 0;
#pragma unroll
                for (int b2 = 0; b2 < 32; ++b2) sl += (__shfl(liIncl, b2) <= idx) ? 1 : 0;
                const int lrow = listL[sl * 1024 + idx - __shfl(liExcl, sl)];
                const int ltok = x[lrow * 16];
                short8 aE = *(const short8*)&embH[__shfl(ltok, n) * 32 + q * 8];
                // comb = relu(emb @ Wc1^T + bc) -> LDS [16][40]
#pragma unroll
                for (int tl2 = 0; tl2 < 2; ++tl2) {
                    short8 b1 = *(const short8*)&wc1[(tl2 * 16 + n) * 32 + q * 8];
                    f4 t0 = MFMA16(aE, b1, bcV[tl2]);
                    short p0, p1, p2, p3;
                    pk2bf(fmaxf(t0[0], 0.f), fmaxf(t0[1], 0.f), p0, p1);
                    pk2bf(fmaxf(t0[2], 0.f), fmaxf(t0[3], 0.f), p2, p3);
                    short* db = &cmbL[(q * 4) * 40 + tl2 * 16 + n];
                    db[0 * 40] = p0; db[1 * 40] = p1; db[2 * 40] = p2; db[3 * 40] = p3;
                }
                CFENCE();
                short8 cA = *(const short8*)&cmbL[n * 40 + q * 8];
                f4 a3[4];
#pragma unroll
                for (int tl3 = 0; tl3 < 4; ++tl3) {
                    short8 bW = *(const short8*)&wth[(tl3 * 16 + n) * 32 + q * 8];
                    a3[tl3] = MFMA16(cA, bW, btV[tl3]);
                }
#pragma unroll
                for (int r = 0; r < 4; ++r) {
                    float l0 = a3[0][r], l1 = a3[1][r], l2 = a3[2][r], l3 = a3[3][r];
                    float mx = fmaxf(fmaxf(l0, l1), fmaxf(l2, l3));
#pragma unroll
                    for (int o2 = 8; o2; o2 >>= 1) mx = fmaxf(mx, __shfl_xor(mx, o2));
                    float sm = __expf(l0 - mx) + __expf(l1 - mx) +
                               __expf(l2 - mx) + __expf(l3 - mx);
#pragma unroll
                    for (int o2 = 8; o2; o2 >>= 1) sm += __shfl_xor(sm, o2);
                    float lse = mx + __logf(sm);
                    int rowO = __shfl(lrow, q * 4 + r);
                    if (base + q * 4 + r < nL) {
                        out[rowO * 64 + n] = l0 - lse;
                        out[rowO * 64 + 16 + n] = l1 - lse;
                        out[rowO * 64 + 32 + n] = l2 - lse;
                        out[rowO * 64 + 48 + n] = l3 - lse;
                    }
                }
                CFENCE();
            }
        }
    }
}

// ---------------- fallback (small ws): monolithic fp32 kernel ----------------
__global__ __launch_bounds__(512) void tagger_fallback(
    const int* __restrict__ x, const int* __restrict__ s, const float* __restrict__ emb,
    const float* __restrict__ Wih, const float* __restrict__ Whh,
    const float* __restrict__ bih, const float* __restrict__ bhh,
    const float* __restrict__ h0, const float* __restrict__ c0,
    const float* __restrict__ Wc, const float* __restrict__ bc,
    const float* __restrict__ Wt, const float* __restrict__ bt,
    float* __restrict__ out) {
    __shared__ float4 WhhP[4096];
    __shared__ float combBuf[8][128];
    for (int i = threadIdx.x; i < 4096; i += 512) {
        int k = i & 63, jj = i >> 6;
        WhhP[k * 64 + jj] = make_float4(Whh[jj * 64 + k], Whh[(jj + 64) * 64 + k],
                                        Whh[(jj + 128) * 64 + k], Whh[(jj + 192) * 64 + k]);
    }
    __syncthreads();
    const int wave = threadIdx.x >> 6, j = threadIdx.x & 63, jm = j & 31;
    const int b = blockIdx.x * 8 + wave;
    const int sv = s[b];
    const int* xb = x + b * NT;
    const float bcj = bc[jm];
    auto rc_val = [&](int tok) -> float {
        float r = 0.f;
#pragma unroll
        for (int k = 0; k < 32; ++k) r = fmaf(emb[tok * NE + k], Wc[jm * 96 + k], r);
        return r;
    };
    float comb4;
    if (sv >= 4) {
        const float h0j = h0[j], c0j = c0[j];
        float4 bsj = make_float4(bih[j] + bhh[j], bih[j + 64] + bhh[j + 64],
                                 bih[j + 128] + bhh[j + 128], bih[j + 192] + bhh[j + 192]);
#pragma unroll 1
        for (int node = 0; node < 4; ++node) {
            float h = h0j, c = c0j;
#pragma unroll 1
            for (int t = 0; t < 4; ++t) {
                int tok = xb[node * 4 + t];
                float4 p = bsj;
#pragma unroll
                for (int k = 0; k < 32; ++k) {
                    float e = emb[tok * NE + k];
                    p.x = fmaf(e, Wih[j * 32 + k], p.x);
                    p.y = fmaf(e, Wih[(j + 64) * 32 + k], p.y);
                    p.z = fmaf(e, Wih[(j + 128) * 32 + k], p.z);
                    p.w = fmaf(e, Wih[(j + 192) * 32 + k], p.w);
                }
                float4 a = make_float4(0.f, 0.f, 0.f, 0.f);
#pragma unroll
                for (int k = 0; k < 64; ++k) {
                    float hk = __shfl(h, k);
                    float4 w = WhhP[k * 64 + j];
                    a.x = fmaf(hk, w.x, a.x); a.y = fmaf(hk, w.y, a.y);
                    a.z = fmaf(hk, w.z, a.z); a.w = fmaf(hk, w.w, a.w);
                }
                a.x += p.x; a.y += p.y; a.z += p.z; a.w += p.w;
                float ig = sigm_(a.x), fg = sigm_(a.y), gg = tanh2_(a.z), og = sigm_(a.w);
                c = fmaf(fg, c, ig * gg);
                h = og * tanh2_(c);
            }
            float last = fmaxf(h, 0.f);
            float acc = rc_val(xb[node * 4]) + bcj;
#pragma unroll
            for (int k = 0; k < 64; ++k)
                acc = fmaf(__shfl(last, k), Wc[jm * 96 + 32 + k], acc);
            if (j < 32) combBuf[wave][node * 32 + j] = fmaxf(acc, 0.f);
        }
        LDSSYNC();
        float h = h0j, c = c0j;
#pragma unroll 1
        for (int t = 0; t < 4; ++t) {
            float4 a = make_float4(0.f, 0.f, 0.f, 0.f);
#pragma unroll
            for (int k = 0; k < 32; ++k) {
                float ck = combBuf[wave][t * 32 + k];
                a.x = fmaf(ck, Wih[j * 32 + k], a.x);
                a.y = fmaf(ck, Wih[(j + 64) * 32 + k], a.y);
                a.z = fmaf(ck, Wih[(j + 128) * 32 + k], a.z);
                a.w = fmaf(ck, Wih[(j + 192) * 32 + k], a.w);
            }
#pragma unroll
            for (int k = 0; k < 64; ++k) {
                float hk = __shfl(h, k);
                float4 w = WhhP[k * 64 + j];
                a.x = fmaf(hk, w.x, a.x); a.y = fmaf(hk, w.y, a.y);
                a.z = fmaf(hk, w.z, a.z); a.w = fmaf(hk, w.w, a.w);
            }
            a.x += bih[j] + bhh[j]; a.y += bih[j + 64] + bhh[j + 64];
            a.z += bih[j + 128] + bhh[j + 128]; a.w += bih[j + 192] + bhh[j + 192];
            float ig = sigm_(a.x), fg = sigm_(a.y), gg = tanh2_(a.z), og = sigm_(a.w);
            c = fmaf(fg, c, ig * gg);
            h = og * tanh2_(c);
        }
        float last = fmaxf(h, 0.f);
        float acc = rc_val(xb[0]) + bcj;
#pragma unroll
        for (int k = 0; k < 64; ++k)
            acc = fmaf(__shfl(last, k), Wc[jm * 96 + 32 + k], acc);
        comb4 = fmaxf(acc, 0.f);
    } else {
        comb4 = fmaxf(rc_val(xb[0]) + bcj, 0.f);
    }
    float logit = bt[j];
    const float* wtr = Wt + j * 32;
#pragma unroll
    for (int k = 0; k < 32; ++k) logit = fmaf(__shfl(comb4, k), wtr[k], logit);
    float mx = logit;
#pragma unroll
    for (int off = 32; off; off >>= 1) mx = fmaxf(mx, __shfl_xor(mx, off));
    float ex = __expf(logit - mx);
    float sum = ex;
#pragma unroll
    for (int off = 32; off; off >>= 1) sum += __shfl_xor(sum, off);
    out[b * 64 + j] = logit - mx - __logf(sum);
}

extern "C" void kernel_launch(void* const* d_in, const int* in_sizes, int n_in,
                              void* d_out, int out_size, void* d_ws, size_t ws_size,
                              hipStream_t stream) {
    const int* x = (const int*)d_in[0];
    const int* s = (const int*)d_in[1];
    const float* emb = (const float*)d_in[2];
    const float* Wih = (const float*)d_in[3];
    const float* Whh = (const float*)d_in[4];
    const float* bih = (const float*)d_in[5];
    const float* bhh = (const float*)d_in[6];
    const float* h0 = (const float*)d_in[7];
    const float* c0 = (const float*)d_in[8];
    const float* Wc = (const float*)d_in[9];
    const float* bc = (const float*)d_in[10];
    const float* Wt = (const float*)d_in[11];
    const float* bt = (const float*)d_in[12];
    float* out = (float*)d_out;

    auto al16 = [](size_t v) { return (v + 15) & ~(size_t)15; };
    size_t off = 0;
    size_t oWpack = off; off = al16(off + (size_t)28672 * 2);  // WhhHi[256x72]+WihHi[256x40]
    size_t oWc1 = off;   off = al16(off + 1024 * 2);
    size_t oWc2 = off;   off = al16(off + 2048 * 2);
    size_t oWt = off;    off = al16(off + 2048 * 2);
    size_t oBsum = off;  off = al16(off + 256 * 4);
    size_t oEmbH = off;  off = al16(off + (size_t)NV * NE * 2);
    size_t oCH = off;    off = al16(off + 32 * 4);
    size_t oListH = off; off = al16(off + (size_t)NB * 4);
    size_t oListL = off; off = al16(off + (size_t)NB * 4);
    size_t need = off;

    char* ws = (char*)d_ws;
    if (ws_size >= need) {
        short* wpack = (short*)(ws + oWpack);
        short* wc1 = (short*)(ws + oWc1);
        short* wc2 = (short*)(ws + oWc2);
        short* wth = (short*)(ws + oWt);
        float* bsum = (float*)(ws + oBsum);
        short* embH = (short*)(ws + oEmbH);
        int* cHp = (int*)(ws + oCH);
        int* listH = (int*)(ws + oListH);
        int* listL = (int*)(ws + oListL);

        classify_prep<<<dim3(256), dim3(1024), 0, stream>>>(
            s, emb, Wih, Whh, bih, bhh, Wc, Wt,
            embH, wpack, wc1, wc2, wth, bsum, cHp, listH, listL);
        main_fused<<<dim3(512), dim3(256), 0, stream>>>(
            x, emb, h0, c0, Wc, bc, Wt, bt, bsum,
            wpack, wc1, wc2, wth, embH, cHp, listH, listL, out);
    } else {
        tagger_fallback<<<dim3(4096), dim3(512), 0, stream>>>(
            x, s, emb, Wih, Whh, bih, bhh, h0, c0, Wc, bc, Wt, bt, out);
    }
}

// Round 9
// 127.170 us; speedup vs baseline: 1.0499x; 1.0499x over previous
//
#include <hip/hip_runtime.h>

// Problem constants
#define NB 32768
#define NT 16
#define NV 32001   // V+1
#define NE 32
#define NTAGS 64

typedef __attribute__((ext_vector_type(8))) short short8;   // 8 bf16 (4 VGPR)
typedef __attribute__((ext_vector_type(4))) float f4;       // MFMA acc

#define MFMA16(a, b, c) __builtin_amdgcn_mfma_f32_16x16x32_bf16(a, b, c, 0, 0, 0)
// DS ops are in-order within a wave -> compiler-only fence suffices for same-wave LDS RAW
#define CFENCE() asm volatile("" ::: "memory")
#define LDSSYNC() asm volatile("s_waitcnt lgkmcnt(0)" ::: "memory")

#define NL2E  (-1.44269504f)   // -log2(e)
#define NL2E2 (-2.88539008f)   // -2*log2(e)

__device__ __forceinline__ float exp2_(float x) {  // raw v_exp_f32 (D = 2^S0)
    float r;
    asm("v_exp_f32 %0, %1" : "=v"(r) : "v"(x));
    return r;
}
__device__ __forceinline__ float sigm_(float x) {
    return __builtin_amdgcn_rcpf(1.0f + __expf(-x));
}
__device__ __forceinline__ float tanh2_(float x) {  // 2*sigm(2x)-1
    float e = __expf(-2.0f * x);
    return fmaf(2.0f, __builtin_amdgcn_rcpf(1.0f + e), -1.0f);
}
__device__ __forceinline__ float tanh2e_(float x) {  // tanh via exp2: one mul on the chain
    return fmaf(2.0f, __builtin_amdgcn_rcpf(1.0f + exp2_(x * NL2E2)), -1.0f);
}
__device__ __forceinline__ short f2bf(float x) {  // RNE float->bf16 bits
    union { float f; unsigned u; } v; v.f = x;
    unsigned r = v.u + 0x7fffu + ((v.u >> 16) & 1u);
    return (short)(r >> 16);
}
// packed RNE float2->bf16x2 (gfx950 v_cvt_pk_bf16_f32; bit-identical to f2bf for normals)
__device__ __forceinline__ void pk2bf(float a, float b, short& lo, short& hi) {
    unsigned r;
    asm("v_cvt_pk_bf16_f32 %0, %1, %2" : "=v"(r) : "v"(a), "v"(b));
    lo = (short)r;
    hi = (short)(r >> 16);
}

// ---------------- K1: classify (32 slabs, no atomics) + emb->bf16 + weight pack ----------------
__global__ __launch_bounds__(1024) void classify_prep(
    const int* __restrict__ s, const float* __restrict__ emb,
    const float* __restrict__ Wih, const float* __restrict__ Whh,
    const float* __restrict__ bih, const float* __restrict__ bhh,
    const float* __restrict__ Wc, const float* __restrict__ Wt,
    short* __restrict__ embH, short* __restrict__ wpack, short* __restrict__ wc1,
    short* __restrict__ wc2, short* __restrict__ wth, float* __restrict__ bsum,
    int* __restrict__ cH, int* __restrict__ listH, int* __restrict__ listL) {
    __shared__ int wbH[16], wbL[16];
    const int tid = threadIdx.x, b = blockIdx.x;
    if (b < 32) {
        const int row = b * 1024 + tid;
        const bool heavy = s[row] >= 4;
        unsigned long long mk = __ballot(heavy);
        const int wv = tid >> 6, ln = tid & 63;
        if (ln == 0) wbH[wv] = __popcll(mk);
        __syncthreads();
        if (tid == 0) {
            int tH = 0, tL = 0;
#pragma unroll
            for (int i = 0; i < 16; ++i) {
                int ch = wbH[i];
                wbH[i] = tH; wbL[i] = tL;
                tH += ch; tL += 64 - ch;
            }
            cH[b] = tH;
        }
        __syncthreads();
        unsigned long long ltm = (1ull << ln) - 1ull;
        if (heavy) listH[b * 1024 + wbH[wv] + __popcll(mk & ltm)] = row;
        else       listL[b * 1024 + wbL[wv] + __popcll((~mk) & ltm)] = row;
    }
    // emb -> bf16: one float4 -> short4 per thread (256008 float4s <= 262144 threads)
    {
        const int i4 = b * 1024 + tid;
        if (i4 < (NV * NE) / 4) {
            const float4 vs = ((const float4*)emb)[i4];
            short p0, p1, p2, p3;
            pk2bf(vs.x, vs.y, p0, p1);
            pk2bf(vs.z, vs.w, p2, p3);
            short4 o; o.x = p0; o.y = p1; o.z = p2; o.w = p3;
            ((short4*)embH)[i4] = o;
        }
    }
    if (b == 32) {        // Whh -> wpack[256][72] (zero-padded)
        for (int t = tid; t < 18432; t += 1024) {
            int r = t / 72, c = t % 72;
            wpack[t] = f2bf(c < 64 ? Whh[r * 64 + c] : 0.f);
        }
    } else if (b == 33) { // Wih -> wpack+18432 [256][40] (zero-padded)
        for (int t = tid; t < 10240; t += 1024) {
            int r = t / 40, c = t % 40;
            wpack[18432 + t] = f2bf(c < 32 ? Wih[r * 32 + c] : 0.f);
        }
    } else if (b == 34) { // Wc split
        if (tid < 1024) { int r = tid >> 5, c = tid & 31; wc1[tid] = f2bf(Wc[r * 96 + c]); }
        for (int t = tid; t < 2048; t += 1024) {
            int r = t >> 6, c = t & 63;
            wc2[t] = f2bf(Wc[r * 96 + 32 + c]);
        }
    } else if (b == 35) { // Wt + bias sum
        for (int t = tid; t < 2048; t += 1024) {
            int r = t >> 5, c = t & 31;
            wth[t] = f2bf(Wt[r * 32 + c]);
        }
        if (tid < 256) bsum[tid] = bih[tid] + bhh[tid];
    }
}

// ---------------- K2: fused main — heavy (block-cooperative, 16 rows/block) + light (MFMA) -----
// __launch_bounds__(256, 2). R9: REVERT of R8's wihP whole-section hoist (it spilled: FETCH
// 9.2->27.3MB, WRITE 8.2->41MB, main 42.9->51us — launch_bounds caps alloc so the allocator
// spills instead of growing). Wih frags are re-loaded per halfStep from L2-resident wihG
// (R7 structure). KEPT from R8: (b) c4 computed redundantly per-wave, no barrier; (c) tanh on
// the c-chain via exp2. Phase-2 keeps R7's aC-MFMA one-step pipeline.
__global__ __launch_bounds__(256, 2) void main_fused(
    const int* __restrict__ x, const float* __restrict__ emb,
    const float* __restrict__ h0, const float* __restrict__ c0,
    const float* __restrict__ Wc, const float* __restrict__ bc,
    const float* __restrict__ Wt, const float* __restrict__ bt,
    const float* __restrict__ bsum,
    const short* __restrict__ wpack, const short* __restrict__ wc1,
    const short* __restrict__ wc2, const short* __restrict__ wth,
    const short* __restrict__ embH, const int* __restrict__ cH,
    const int* __restrict__ listH, const int* __restrict__ listL,
    float* __restrict__ out) {
    __shared__ __align__(16) short sWhh[18432];      // 36 KB [256][72] bf16
    __shared__ __align__(16) short sHA[4][16 * 72];  // phase1: per-wave h; phase2: sHA[0]/sHA[1] dbuf
    __shared__ __align__(16) short sCmb[4][16 * 40]; // heavy: block cmbB[node*16+row][40]; light: per-wave
    __shared__ __align__(16) short sC4[4][4 * 40];   // heavy: block c4[16 rows][40]
    __shared__ int sRow[16];                         // heavy: global row ids of the block's 16 rows

    const int tid = threadIdx.x, wave = tid >> 6, lane = tid & 63;
    const int q = lane >> 4, n = lane & 15;
    const int NW = gridDim.x * 4;  // 2048
    const int gw = blockIdx.x * 4 + wave;

    // 32-slab prefix scan (per wave, shfl)
    int cs = (lane < 32) ? cH[lane] : 0;
    int v = cs;
#pragma unroll
    for (int o = 1; o < 32; o <<= 1) { int t2 = __shfl_up(v, o); if (lane >= o) v += t2; }
    const int vIncl = v, vExcl = v - cs;
    const int nH = __shfl(vIncl, 31);
    const int nL = NB - nH;
    const int liIncl = (lane + 1) * 1024 - vIncl;  // light prefixes (lane<32)
    const int liExcl = lane * 1024 - vExcl;
    const int nHB = (nH + 15) >> 4;                // heavy BLOCK count (16 rows/block)
    const bool heavyBlk = (int)blockIdx.x < nHB;
    const short* wihG = wpack + 18432;             // Wih [256][40] bf16 — global (L2-resident)

    // ---- prologue hoist: first heavy iteration's gathers issued BEFORE staging ----
    int row0 = 0, tokAll0 = 0;
    short8 aNext0;
    const int liBase = (n & 3) * 16 + (n >> 2) * 4;  // unit n: row n&3, node n>>2
    if (heavyBlk) {
        int idxq = min((int)blockIdx.x * 16 + wave * 4 + q, nH - 1);
        int sl = 0;
#pragma unroll
        for (int b2 = 0; b2 < 32; ++b2) sl += (__shfl(vIncl, b2) <= idxq) ? 1 : 0;
        row0 = listH[sl * 1024 + idxq - __shfl(vExcl, sl)];
        tokAll0 = x[row0 * 16 + n];
        aNext0 = *(const short8*)&embH[__shfl(tokAll0, liBase) * 32 + q * 8];
    }

    if (heavyBlk) {  // block-uniform: only heavy blocks stage Whh
        for (int i = tid; i < 2304; i += 256)
            ((uint4*)sWhh)[i] = ((const uint4*)wpack)[i];
        __syncthreads();
    }

    if (heavyBlk) {
        short* hA = sHA[wave];        // phase1 private slice
        short* cmbB = sCmb[0];        // [64][40] block-level: node*16 + blockrow
        short* c4 = sC4[0];           // [16][40] block-level

        // scaled gate biases: tiles 0-7 (i,f) and 12-15 (o): -log2e*b; tiles 8-11 (g): -2log2e*b
        float sb16[16];
#pragma unroll
        for (int tl = 0; tl < 16; ++tl)
            sb16[tl] = (((tl >> 2) == 2) ? NL2E2 : NL2E) * bsum[tl * 16 + n];
        float bc2[2] = {bc[n], bc[16 + n]};
        float bt4[4] = {bt[n], bt[16 + n], bt[32 + n], bt[48 + n]};
        float c0v[4];
#pragma unroll
        for (int u = 0; u < 4; ++u) c0v[u] = c0[u * 16 + n];
        // h0 A-fragments (step-0 Whh operand is h0 for every row)
        short8 h0f0, h0f1;
#pragma unroll
        for (int j = 0; j < 8; ++j) {
            h0f0[j] = f2bf(h0[q * 8 + j]);
            h0f1[j] = f2bf(h0[32 + q * 8 + j]);
        }
        const float c0w = c0[wave * 16 + n];  // phase2: this wave's unit block

        const f4 zero4 = {0.f, 0.f, 0.f, 0.f};
        float cst[4][4];

        // one half-step: 8 tiles {g*4+u0, g*4+u0+1 : g in 0..3}, gate updates for u0,u0+1.
        // Wih frags loaded HERE (short live range — R8's whole-section hoist spilled).
        auto halfStep = [&](int u0, short8 aP, short8 ah0, short8 ah1, bool doRelu) {
            short8 wihF[8];
#pragma unroll
            for (int g = 0; g < 4; ++g)
#pragma unroll
                for (int k = 0; k < 2; ++k)
                    wihF[g * 2 + k] =
                        *(const short8*)&wihG[((g * 4 + u0 + k) * 16 + n) * 40 + q * 8];
            f4 acc8[8];
#pragma unroll
            for (int j = 0; j < 8; ++j) acc8[j] = MFMA16(aP, wihF[j], zero4);
#pragma unroll
            for (int g = 0; g < 4; ++g)
#pragma unroll
                for (int k = 0; k < 2; ++k) {
                    const short* rbp = &sWhh[((g * 4 + u0 + k) * 16 + n) * 72 + q * 8];
                    f4 t0 = acc8[g * 2 + k];
                    t0 = MFMA16(ah0, *(const short8*)rbp, t0);
                    t0 = MFMA16(ah1, *(const short8*)(rbp + 32), t0);
                    acc8[g * 2 + k] = t0;
                }
#pragma unroll
            for (int k = 0; k < 2; ++k) {
                const int u = u0 + k;
                float hv[4];
#pragma unroll
                for (int r = 0; r < 4; ++r) {
                    float si = __builtin_amdgcn_rcpf(
                        1.0f + exp2_(fmaf(acc8[0 + k][r], NL2E, sb16[u])));
                    float sf = __builtin_amdgcn_rcpf(
                        1.0f + exp2_(fmaf(acc8[2 + k][r], NL2E, sb16[4 + u])));
                    float tg = fmaf(2.0f, __builtin_amdgcn_rcpf(
                        1.0f + exp2_(fmaf(acc8[4 + k][r], NL2E2, sb16[8 + u]))), -1.0f);
                    float so = __builtin_amdgcn_rcpf(
                        1.0f + exp2_(fmaf(acc8[6 + k][r], NL2E, sb16[12 + u])));
                    float cc = fmaf(sf, cst[r][u], si * tg);
                    cst[r][u] = cc;
                    float hh = so * tanh2e_(cc);
                    if (doRelu) hh = fmaxf(hh, 0.f);
                    hv[r] = hh;
                }
                short p0, p1, p2, p3;
                pk2bf(hv[0], hv[1], p0, p1);
                pk2bf(hv[2], hv[3], p2, p3);
                hA[(q * 4 + 0) * 72 + u * 16 + n] = p0;
                hA[(q * 4 + 1) * 72 + u * 16 + n] = p1;
                hA[(q * 4 + 2) * 72 + u * 16 + n] = p2;
                hA[(q * 4 + 3) * 72 + u * 16 + n] = p3;
            }
        };

#pragma unroll 1
        for (int itb = blockIdx.x; itb * 16 < nH; itb += (int)gridDim.x) {
            const int base = itb * 16;
            int row, tokAll;
            short8 aNext;
            if (itb == (int)blockIdx.x) {  // wave-uniform branch: use hoisted prologue
                row = row0; tokAll = tokAll0; aNext = aNext0;
            } else {
                int idxq = min(base + wave * 4 + q, nH - 1);
                int sl = 0;
#pragma unroll
                for (int b2 = 0; b2 < 32; ++b2) sl += (__shfl(vIncl, b2) <= idxq) ? 1 : 0;
                row = listH[sl * 1024 + idxq - __shfl(vExcl, sl)];
                tokAll = x[row * 16 + n];
                aNext = *(const short8*)&embH[__shfl(tokAll, liBase) * 32 + q * 8];
            }
            if (n == 0) sRow[wave * 4 + q] = row;       // own slots only (no cross-wave race)
            const int tokR0 = __shfl(tokAll, liBase);   // root token (frag reloaded at comb)

            // ---- phase 1: this wave's 4 rows x 4 nodes in the 16 units, 4 steps ----
#pragma unroll
            for (int u = 0; u < 4; ++u)
#pragma unroll
                for (int r = 0; r < 4; ++r) cst[r][u] = c0v[u];
            short8 a0 = h0f0, a1 = h0f1;
#pragma unroll 1
            for (int t = 0; t < 4; ++t) {
                short8 aP = aNext;
                if (t < 3) {
                    int tk2 = __shfl(tokAll, liBase + t + 1);
                    aNext = *(const short8*)&embH[tk2 * 32 + q * 8];
                }
                halfStep(0, aP, a0, a1, t == 3);
                halfStep(2, aP, a0, a1, t == 3);  // step 3 writes relu(h) = "last"
                CFENCE();                          // order h ds_writes before the re-read below
                if (t < 3) {
                    a0 = *(const short8*)&hA[n * 72 + q * 8];
                    a1 = *(const short8*)&hA[n * 72 + 32 + q * 8];
                }
            }
            // comb for 16 (node,row) pairs -> block cmbB[node*16 + blockrow][40]
            {
                short8 aRoot = *(const short8*)&embH[tokR0 * 32 + q * 8];  // L2-resident reload
                short8 lh0 = *(const short8*)&hA[n * 72 + q * 8];
                short8 lh1 = *(const short8*)&hA[n * 72 + 32 + q * 8];
#pragma unroll
                for (int tl2 = 0; tl2 < 2; ++tl2) {
                    float bv = bc2[tl2];
                    f4 t0 = {bv, bv, bv, bv};
                    short8 b1 = *(const short8*)&wc1[(tl2 * 16 + n) * 32 + q * 8];
                    t0 = MFMA16(aRoot, b1, t0);
                    const short* rbp = &wc2[(tl2 * 16 + n) * 64 + q * 8];
                    t0 = MFMA16(lh0, *(const short8*)rbp, t0);
                    t0 = MFMA16(lh1, *(const short8*)(rbp + 32), t0);
                    // node = q, local rows r consecutive -> pack converts
                    short p0, p1, p2, p3;
                    pk2bf(fmaxf(t0[0], 0.f), fmaxf(t0[1], 0.f), p0, p1);
                    pk2bf(fmaxf(t0[2], 0.f), fmaxf(t0[3], 0.f), p2, p3);
                    short* db = &cmbB[(q * 16 + wave * 4) * 40 + tl2 * 16 + n];
                    db[0 * 40] = p0; db[1 * 40] = p1; db[2 * 40] = p2; db[3 * 40] = p3;
                }
            }
            // phase2-invariant B-frags + scaled bias: hoist BEFORE barrier (whh from LDS, wih
            // from global; acc AGPRs are dead past comb)
            float sb4[4];
            short8 wih2[4], whhA[4], whhB[4];
#pragma unroll
            for (int j = 0; j < 4; ++j) {
                sb4[j] = ((j == 2) ? NL2E2 : NL2E) * bsum[(j * 4 + wave) * 16 + n];
                wih2[j] = *(const short8*)&wihG[((j * 4 + wave) * 16 + n) * 40 + q * 8];
                const short* rbp = &sWhh[((j * 4 + wave) * 16 + n) * 72 + q * 8];
                whhA[j] = *(const short8*)rbp;
                whhB[j] = *(const short8*)(rbp + 32);
            }
            __syncthreads();  // cmbB + sRow complete; per-wave hA free after this point

            // ---- phase 2: node 4 for all 16 block rows, unit-block = wave; ROLLED loop,
            //      aC-MFMA pipelined one step ahead (independent of the h barrier chain) ----
            {
                float cstw[4] = {c0w, c0w, c0w, c0w};
                short8 b0 = h0f0, b1 = h0f1;
                f4 acPre[4];
                {
                    short8 aC0 = *(const short8*)&cmbB[(0 * 16 + n) * 40 + q * 8];
#pragma unroll
                    for (int j = 0; j < 4; ++j) acPre[j] = MFMA16(aC0, wih2[j], zero4);
                }
                short8 aCn = *(const short8*)&cmbB[(1 * 16 + n) * 40 + q * 8];
#pragma unroll 1
                for (int t = 0; t < 4; ++t) {
                    short* hbw = (t & 1) ? sHA[1] : sHA[0];  // ternary select (reg, no scratch)
                    f4 ac4[4];
#pragma unroll
                    for (int j = 0; j < 4; ++j) {
                        f4 t0 = MFMA16(b0, whhA[j], acPre[j]);
                        t0 = MFMA16(b1, whhB[j], t0);
                        ac4[j] = t0;
                    }
                    // prefetch next step's aC products (h-independent; t=3's is dead work)
#pragma unroll
                    for (int j = 0; j < 4; ++j) acPre[j] = MFMA16(aCn, wih2[j], zero4);
                    aCn = *(const short8*)&cmbB[(((t + 2) & 3) * 16 + n) * 40 + q * 8];
                    float hv[4];
#pragma unroll
                    for (int r = 0; r < 4; ++r) {
                        float si = __builtin_amdgcn_rcpf(
                            1.0f + exp2_(fmaf(ac4[0][r], NL2E, sb4[0])));
                        float sf = __builtin_amdgcn_rcpf(
                            1.0f + exp2_(fmaf(ac4[1][r], NL2E, sb4[1])));
                        float tg = fmaf(2.0f, __builtin_amdgcn_rcpf(
                            1.0f + exp2_(fmaf(ac4[2][r], NL2E2, sb4[2]))), -1.0f);
                        float so = __builtin_amdgcn_rcpf(
                            1.0f + exp2_(fmaf(ac4[3][r], NL2E, sb4[3])));
                        float cc = fmaf(sf, cstw[r], si * tg);
                        cstw[r] = cc;
                        float hh = so * tanh2e_(cc);
                        if (t == 3) hh = fmaxf(hh, 0.f);
                        hv[r] = hh;
                    }
                    short p0, p1, p2, p3;
                    pk2bf(hv[0], hv[1], p0, p1);
                    pk2bf(hv[2], hv[3], p2, p3);
                    hbw[(q * 4 + 0) * 72 + wave * 16 + n] = p0;
                    hbw[(q * 4 + 1) * 72 + wave * 16 + n] = p1;
                    hbw[(q * 4 + 2) * 72 + wave * 16 + n] = p2;
                    hbw[(q * 4 + 3) * 72 + wave * 16 + n] = p3;
                    __syncthreads();  // all unit slices of this step visible (full fence)
                    b0 = *(const short8*)&hbw[n * 72 + q * 8];
                    b1 = *(const short8*)&hbw[n * 72 + 32 + q * 8];
                }
            }

            // ---- c4 = relu([root,last]@Wc^T+bc) for 16 rows. ALL inputs are identical across
            //      waves (barrier-synced), so every wave writes its own full copy (same bytes,
            //      benign) and reads it back with only an in-wave fence — NO barrier. ----
            {
                const short* hL = sHA[1];  // t=3 buffer
                int rv = sRow[n];
                int tokR = x[rv * 16];
                short8 aR = *(const short8*)&embH[tokR * 32 + q * 8];
                short8 lb0 = *(const short8*)&hL[n * 72 + q * 8];
                short8 lb1 = *(const short8*)&hL[n * 72 + 32 + q * 8];
#pragma unroll
                for (int tl2 = 0; tl2 < 2; ++tl2) {
                    float bv = bc2[tl2];
                    f4 t0 = {bv, bv, bv, bv};
                    short8 b1f = *(const short8*)&wc1[(tl2 * 16 + n) * 32 + q * 8];
                    t0 = MFMA16(aR, b1f, t0);
                    const short* rbp = &wc2[(tl2 * 16 + n) * 64 + q * 8];
                    t0 = MFMA16(lb0, *(const short8*)rbp, t0);
                    t0 = MFMA16(lb1, *(const short8*)(rbp + 32), t0);
                    short p0, p1, p2, p3;
                    pk2bf(fmaxf(t0[0], 0.f), fmaxf(t0[1], 0.f), p0, p1);
                    pk2bf(fmaxf(t0[2], 0.f), fmaxf(t0[3], 0.f), p2, p3);
                    short* db = &c4[(q * 4) * 40 + tl2 * 16 + n];  // quad q owns rows q*4+r
                    db[0 * 40] = p0; db[1 * 40] = p1; db[2 * 40] = p2; db[3 * 40] = p3;
                }
            }
            CFENCE();  // same-wave DS in-order: our own 16-row copy is readable

            // ---- phase 3: logits + log_softmax for 16 rows (dup compute, split writes) ----
            {
                short8 cA = *(const short8*)&c4[n * 40 + q * 8];
                f4 a3[4];
#pragma unroll
                for (int tl3 = 0; tl3 < 4; ++tl3) {
                    float bv = bt4[tl3];
                    f4 t0 = {bv, bv, bv, bv};
                    short8 bW = *(const short8*)&wth[(tl3 * 16 + n) * 32 + q * 8];
                    a3[tl3] = MFMA16(cA, bW, t0);
                }
#pragma unroll
                for (int r = 0; r < 4; ++r) {
                    float l0 = a3[0][r], l1 = a3[1][r], l2 = a3[2][r], l3 = a3[3][r];
                    float mx = fmaxf(fmaxf(l0, l1), fmaxf(l2, l3));
#pragma unroll
                    for (int o2 = 8; o2; o2 >>= 1) mx = fmaxf(mx, __shfl_xor(mx, o2));
                    float sm = __expf(l0 - mx) + __expf(l1 - mx) +
                               __expf(l2 - mx) + __expf(l3 - mx);
#pragma unroll
                    for (int o2 = 8; o2; o2 >>= 1) sm += __shfl_xor(sm, o2);
                    float lse = mx + __logf(sm);
                    if (q == wave && base + wave * 4 + r < nH) {
                        int ro = sRow[wave * 4 + r];
                        out[ro * 64 + n] = l0 - lse;
                        out[ro * 64 + 16 + n] = l1 - lse;
                        out[ro * 64 + 32 + n] = l2 - lse;
                        out[ro * 64 + 48 + n] = l3 - lse;
                    }
                }
            }
            // guard next iteration's shared writes vs this iteration's reads (multi-iter only;
            // with grid == nHB this is dead code)
            if ((itb + (int)gridDim.x) * 16 < nH) __syncthreads();
        }
    }

    // ---- light rows: 16 rows/iteration via MFMA, reverse-mapped over ALL waves so light
    //      overlaps the heavy tail (heavy waves pick up light as they finish) ----
    if (nL > 0) {
        const int lw = NW - 1 - gw;
        const int base0 = lw * 16;
        if (base0 < nL) {
            short* cmbL = sCmb[wave];  // safe: all waves of this block are past phase-2 reads
            f4 bcV[2], btV[4];
#pragma unroll
            for (int t = 0; t < 2; ++t) { float bv = bc[t * 16 + n]; bcV[t] = f4{bv, bv, bv, bv}; }
#pragma unroll
            for (int t = 0; t < 4; ++t) { float bv = bt[t * 16 + n]; btV[t] = f4{bv, bv, bv, bv}; }
#pragma unroll 1
            for (int base = base0; base < nL; base += NW * 16) {
                int idx = min(base + (lane & 15), nL - 1);  // 16 rows only (no 4x gather waste)
                int sl = 0;
#pragma unroll
                for (int b2 = 0; b2 < 32; ++b2) sl += (__shfl(liIncl, b2) <= idx) ? 1 : 0;
                const int lrow = listL[sl * 1024 + idx - __shfl(liExcl, sl)];
                const int ltok = x[lrow * 16];
                short8 aE = *(const short8*)&embH[__shfl(ltok, n) * 32 + q * 8];
                // comb = relu(emb @ Wc1^T + bc) -> LDS [16][40]
#pragma unroll
                for (int tl2 = 0; tl2 < 2; ++tl2) {
                    short8 b1 = *(const short8*)&wc1[(tl2 * 16 + n) * 32 + q * 8];
                    f4 t0 = MFMA16(aE, b1, bcV[tl2]);
                    short p0, p1, p2, p3;
                    pk2bf(fmaxf(t0[0], 0.f), fmaxf(t0[1], 0.f), p0, p1);
                    pk2bf(fmaxf(t0[2], 0.f), fmaxf(t0[3], 0.f), p2, p3);
                    short* db = &cmbL[(q * 4) * 40 + tl2 * 16 + n];
                    db[0 * 40] = p0; db[1 * 40] = p1; db[2 * 40] = p2; db[3 * 40] = p3;
                }
                CFENCE();
                short8 cA = *(const short8*)&cmbL[n * 40 + q * 8];
                f4 a3[4];
#pragma unroll
                for (int tl3 = 0; tl3 < 4; ++tl3) {
                    short8 bW = *(const short8*)&wth[(tl3 * 16 + n) * 32 + q * 8];
                    a3[tl3] = MFMA16(cA, bW, btV[tl3]);
                }
#pragma unroll
                for (int r = 0; r < 4; ++r) {
                    float l0 = a3[0][r], l1 = a3[1][r], l2 = a3[2][r], l3 = a3[3][r];
                    float mx = fmaxf(fmaxf(l0, l1), fmaxf(l2, l3));
#pragma unroll
                    for (int o2 = 8; o2; o2 >>= 1) mx = fmaxf(mx, __shfl_xor(mx, o2));
                    float sm = __expf(l0 - mx) + __expf(l1 - mx) +
                               __expf(l2 - mx) + __expf(l3 - mx);
#pragma unroll
                    for (int o2 = 8; o2; o2 >>= 1) sm += __shfl_xor(sm, o2);
                    float lse = mx + __logf(sm);
                    int rowO = __shfl(lrow, q * 4 + r);
                    if (base + q * 4 + r < nL) {
                        out[rowO * 64 + n] = l0 - lse;
                        out[rowO * 64 + 16 + n] = l1 - lse;
                        out[rowO * 64 + 32 + n] = l2 - lse;
                        out[rowO * 64 + 48 + n] = l3 - lse;
                    }
                }
                CFENCE();
            }
        }
    }
}

// ---------------- fallback (small ws): monolithic fp32 kernel ----------------
__global__ __launch_bounds__(512) void tagger_fallback(
    const int* __restrict__ x, const int* __restrict__ s, const float* __restrict__ emb,
    const float* __restrict__ Wih, const float* __restrict__ Whh,
    const float* __restrict__ bih, const float* __restrict__ bhh,
    const float* __restrict__ h0, const float* __restrict__ c0,
    const float* __restrict__ Wc, const float* __restrict__ bc,
    const float* __restrict__ Wt, const float* __restrict__ bt,
    float* __restrict__ out) {
    __shared__ float4 WhhP[4096];
    __shared__ float combBuf[8][128];
    for (int i = threadIdx.x; i < 4096; i += 512) {
        int k = i & 63, jj = i >> 6;
        WhhP[k * 64 + jj] = make_float4(Whh[jj * 64 + k], Whh[(jj + 64) * 64 + k],
                                        Whh[(jj + 128) * 64 + k], Whh[(jj + 192) * 64 + k]);
    }
    __syncthreads();
    const int wave = threadIdx.x >> 6, j = threadIdx.x & 63, jm = j & 31;
    const int b = blockIdx.x * 8 + wave;
    const int sv = s[b];
    const int* xb = x + b * NT;
    const float bcj = bc[jm];
    auto rc_val = [&](int tok) -> float {
        float r = 0.f;
#pragma unroll
        for (int k = 0; k < 32; ++k) r = fmaf(emb[tok * NE + k], Wc[jm * 96 + k], r);
        return r;
    };
    float comb4;
    if (sv >= 4) {
        const float h0j = h0[j], c0j = c0[j];
        float4 bsj = make_float4(bih[j] + bhh[j], bih[j + 64] + bhh[j + 64],
                                 bih[j + 128] + bhh[j + 128], bih[j + 192] + bhh[j + 192]);
#pragma unroll 1
        for (int node = 0; node < 4; ++node) {
            float h = h0j, c = c0j;
#pragma unroll 1
            for (int t = 0; t < 4; ++t) {
                int tok = xb[node * 4 + t];
                float4 p = bsj;
#pragma unroll
                for (int k = 0; k < 32; ++k) {
                    float e = emb[tok * NE + k];
                    p.x = fmaf(e, Wih[j * 32 + k], p.x);
                    p.y = fmaf(e, Wih[(j + 64) * 32 + k], p.y);
                    p.z = fmaf(e, Wih[(j + 128) * 32 + k], p.z);
                    p.w = fmaf(e, Wih[(j + 192) * 32 + k], p.w);
                }
                float4 a = make_float4(0.f, 0.f, 0.f, 0.f);
#pragma unroll
                for (int k = 0; k < 64; ++k) {
                    float hk = __shfl(h, k);
                    float4 w = WhhP[k * 64 + j];
                    a.x = fmaf(hk, w.x, a.x); a.y = fmaf(hk, w.y, a.y);
                    a.z = fmaf(hk, w.z, a.z); a.w = fmaf(hk, w.w, a.w);
                }
                a.x += p.x; a.y += p.y; a.z += p.z; a.w += p.w;
                float ig = sigm_(a.x), fg = sigm_(a.y), gg = tanh2_(a.z), og = sigm_(a.w);
                c = fmaf(fg, c, ig * gg);
                h = og * tanh2_(c);
            }
            float last = fmaxf(h, 0.f);
            float acc = rc_val(xb[node * 4]) + bcj;
#pragma unroll
            for (int k = 0; k < 64; ++k)
                acc = fmaf(__shfl(last, k), Wc[jm * 96 + 32 + k], acc);
            if (j < 32) combBuf[wave][node * 32 + j] = fmaxf(acc, 0.f);
        }
        LDSSYNC();
        float h = h0j, c = c0j;
#pragma unroll 1
        for (int t = 0; t < 4; ++t) {
            float4 a = make_float4(0.f, 0.f, 0.f, 0.f);
#pragma unroll
            for (int k = 0; k < 32; ++k) {
                float ck = combBuf[wave][t * 32 + k];
                a.x = fmaf(ck, Wih[j * 32 + k], a.x);
                a.y = fmaf(ck, Wih[(j + 64) * 32 + k], a.y);
                a.z = fmaf(ck, Wih[(j + 128) * 32 + k], a.z);
                a.w = fmaf(ck, Wih[(j + 192) * 32 + k], a.w);
            }
#pragma unroll
            for (int k = 0; k < 64; ++k) {
                float hk = __shfl(h, k);
                float4 w = WhhP[k * 64 + j];
                a.x = fmaf(hk, w.x, a.x); a.y = fmaf(hk, w.y, a.y);
                a.z = fmaf(hk, w.z, a.z); a.w = fmaf(hk, w.w, a.w);
            }
            a.x += bih[j] + bhh[j]; a.y += bih[j + 64] + bhh[j + 64];
            a.z += bih[j + 128] + bhh[j + 128]; a.w += bih[j + 192] + bhh[j + 192];
            float ig = sigm_(a.x), fg = sigm_(a.y), gg = tanh2_(a.z), og = sigm_(a.w);
            c = fmaf(fg, c, ig * gg);
            h = og * tanh2_(c);
        }
        float last = fmaxf(h, 0.f);
        float acc = rc_val(xb[0]) + bcj;
#pragma unroll
        for (int k = 0; k < 64; ++k)
            acc = fmaf(__shfl(last, k), Wc[jm * 96 + 32 + k], acc);
        comb4 = fmaxf(acc, 0.f);
    } else {
        comb4 = fmaxf(rc_val(xb[0]) + bcj, 0.f);
    }
    float logit = bt[j];
    const float* wtr = Wt + j * 32;
#pragma unroll
    for (int k = 0; k < 32; ++k) logit = fmaf(__shfl(comb4, k), wtr[k], logit);
    float mx = logit;
#pragma unroll
    for (int off = 32; off; off >>= 1) mx = fmaxf(mx, __shfl_xor(mx, off));
    float ex = __expf(logit - mx);
    float sum = ex;
#pragma unroll
    for (int off = 32; off; off >>= 1) sum += __shfl_xor(sum, off);
    out[b * 64 + j] = logit - mx - __logf(sum);
}

extern "C" void kernel_launch(void* const* d_in, const int* in_sizes, int n_in,
                              void* d_out, int out_size, void* d_ws, size_t ws_size,
                              hipStream_t stream) {
    const int* x = (const int*)d_in[0];
    const int* s = (const int*)d_in[1];
    const float* emb = (const float*)d_in[2];
    const float* Wih = (const float*)d_in[3];
    const float* Whh = (const float*)d_in[4];
    const float* bih = (const float*)d_in[5];
    const float* bhh = (const float*)d_in[6];
    const float* h0 = (const float*)d_in[7];
    const float* c0 = (const float*)d_in[8];
    const float* Wc = (const float*)d_in[9];
    const float* bc = (const float*)d_in[10];
    const float* Wt = (const float*)d_in[11];
    const float* bt = (const float*)d_in[12];
    float* out = (float*)d_out;

    auto al16 = [](size_t v) { return (v + 15) & ~(size_t)15; };
    size_t off = 0;
    size_t oWpack = off; off = al16(off + (size_t)28672 * 2);  // WhhHi[256x72]+WihHi[256x40]
    size_t oWc1 = off;   off = al16(off + 1024 * 2);
    size_t oWc2 = off;   off = al16(off + 2048 * 2);
    size_t oWt = off;    off = al16(off + 2048 * 2);
    size_t oBsum = off;  off = al16(off + 256 * 4);
    size_t oEmbH = off;  off = al16(off + (size_t)NV * NE * 2);
    size_t oCH = off;    off = al16(off + 32 * 4);
    size_t oListH = off; off = al16(off + (size_t)NB * 4);
    size_t oListL = off; off = al16(off + (size_t)NB * 4);
    size_t need = off;

    char* ws = (char*)d_ws;
    if (ws_size >= need) {
        short* wpack = (short*)(ws + oWpack);
        short* wc1 = (short*)(ws + oWc1);
        short* wc2 = (short*)(ws + oWc2);
        short* wth = (short*)(ws + oWt);
        float* bsum = (float*)(ws + oBsum);
        short* embH = (short*)(ws + oEmbH);
        int* cHp = (int*)(ws + oCH);
        int* listH = (int*)(ws + oListH);
        int* listL = (int*)(ws + oListL);

        classify_prep<<<dim3(256), dim3(1024), 0, stream>>>(
            s, emb, Wih, Whh, bih, bhh, Wc, Wt,
            embH, wpack, wc1, wc2, wth, bsum, cHp, listH, listL);
        main_fused<<<dim3(512), dim3(256), 0, stream>>>(
            x, emb, h0, c0, Wc, bc, Wt, bt, bsum,
            wpack, wc1, wc2, wth, embH, cHp, listH, listL, out);
    } else {
        tagger_fallback<<<dim3(4096), dim3(512), 0, stream>>>(
            x, s, emb, Wih, Whh, bih, bhh, h0, c0, Wc, bc, Wt, bt, out);
    }
}